// Round 1
// baseline (1872.368 us; speedup 1.0000x reference)
//
#include <hip/hip_runtime.h>

#define LSEQ 400
#define BATCH 256
#define EMBD 256
#define HIDD 512
#define KDIM 768   // EMB + HID
#define NJ 41      // K+1

typedef __attribute__((ext_vector_type(8))) short short8x;
typedef __attribute__((ext_vector_type(4))) float f32x4;

__device__ __forceinline__ float bf2f(unsigned short u) {
    union { unsigned int i; float f; } v; v.i = ((unsigned int)u) << 16; return v.f;
}
__device__ __forceinline__ unsigned short f2bf(float f) {
    union { float f; unsigned int i; } v; v.f = f;
    unsigned int x = v.i;
    return (unsigned short)((x + 0x7fffu + ((x >> 16) & 1u)) >> 16);
}
__device__ __forceinline__ float sigm(float x) { return 1.0f / (1.0f + __expf(-x)); }

// ---------------------------------------------------------------------------
// Prologue: pack W_ih|W_hh (f32) into bf16 MFMA-fragment order; init state.
// pW layout: [gg(64)][mt(2)][kt(24)][lane(64)] x short8, where the WG "gg"
// owns hidden units [gg*8, gg*8+8), local row r = mt*16 + (lane&15),
// gate = r>>3, hu = r&7, global row = gate*512 + gg*8 + hu,
// k = kt*32 + (lane>>4)*8 + j  (same bijection used on the B side).
// ---------------------------------------------------------------------------
__global__ __launch_bounds__(256) void prologue_kernel(
    const float* __restrict__ W_ih, const float* __restrict__ W_hh,
    const int* __restrict__ xs, const float* __restrict__ embW,
    const float* __restrict__ mask,
    unsigned short* __restrict__ pW, unsigned short* __restrict__ xh0,
    float* __restrict__ c_st, int* __restrict__ base_rows)
{
    int wg = blockIdx.x, t = threadIdx.x;
    int gg = wg >> 2, part = wg & 3;
    int lane = t & 63, sub = t >> 6;
    for (int q = 0; q < 3; ++q) {
        int f = sub * 3 + q;                 // 0..11
        int mt = f / 6, kt = part * 6 + (f % 6);
        int r = mt * 16 + (lane & 15);
        int gate = r >> 3, hu = r & 7;
        int grow = gate * 512 + gg * 8 + hu;
        int k0 = kt * 32 + ((lane >> 4) << 3);
        union { short8x v; unsigned short u[8]; } pk;
        #pragma unroll
        for (int j = 0; j < 8; ++j) {
            int k = k0 + j;
            float wv = (k < EMBD) ? W_ih[(size_t)grow * EMBD + k]
                                  : W_hh[(size_t)grow * HIDD + (k - EMBD)];
            pk.u[j] = f2bf(wv);
        }
        ((short8x*)pW)[((size_t)(gg * 2 + mt) * 24 + kt) * 64 + lane] = pk.v;
    }
    // per-batch state init (b = wg): x for step 0 (row 0), h=0, c=0, base=0
    int b = wg;
    int tok = xs[b];   // row 0
    float ev = embW[(size_t)tok * EMBD + t] * mask[(size_t)b * EMBD + t];
    xh0[(size_t)b * KDIM + t] = f2bf(ev);
    for (int e = t; e < HIDD; e += 256) {
        xh0[(size_t)b * KDIM + EMBD + e] = 0;
        c_st[(size_t)b * HIDD + e] = 0.0f;
    }
    if (t == 0) base_rows[b] = 0;
}

// ---------------------------------------------------------------------------
// One LSTM step. 256 WGs = 64 gate-groups (gg: 8 hidden units) x 4 batch
// groups (bg: 64 cols). Per WG: D(32x64) = Wslice(32x768) @ xh(768x64) via
// mfma_f32_16x16x32_bf16, LDS exchange, elementwise LSTM (freeze-aware),
// then fused gather of next step's x (one batch element per WG).
// ---------------------------------------------------------------------------
__global__ __launch_bounds__(256) void step_kernel(
    const unsigned short* __restrict__ pW,
    const unsigned short* __restrict__ xh_in,
    unsigned short* __restrict__ xh_out,
    float* __restrict__ c_st,
    const int* __restrict__ base_rows,
    const float* __restrict__ b_ih, const float* __restrict__ b_hh,
    const int* __restrict__ xs, const float* __restrict__ embW,
    const float* __restrict__ mask,
    int stepi, int do_gather)
{
    __shared__ float gates[32][65];
    __shared__ __align__(16) unsigned short hstage[64][8];

    int wg = blockIdx.x;
    int gg = wg >> 2, bg = wg & 3;
    int tid = threadIdx.x, lane = tid & 63, w = tid >> 6;
    int mhalf = w >> 1, npair = w & 1;

    const short8x* Ab = ((const short8x*)pW) + ((size_t)(gg * 2 + mhalf) * 24) * 64 + lane;
    int bcol0 = bg * 64 + npair * 32 + (lane & 15);
    int krow  = (lane >> 4) << 3;
    const short8x* B0 = (const short8x*)(xh_in + (size_t)bcol0 * KDIM + krow);
    const short8x* B1 = (const short8x*)(xh_in + (size_t)(bcol0 + 16) * KDIM + krow);

    f32x4 acc0a = {0,0,0,0}, acc0b = {0,0,0,0};
    f32x4 acc1a = {0,0,0,0}, acc1b = {0,0,0,0};
    #pragma unroll
    for (int kt = 0; kt < 24; kt += 2) {          // 2 chains to shorten dep latency
        short8x a0  = Ab[kt * 64];
        short8x a1  = Ab[(kt + 1) * 64];
        short8x b00 = B0[kt * 4];
        short8x b01 = B0[(kt + 1) * 4];
        short8x b10 = B1[kt * 4];
        short8x b11 = B1[(kt + 1) * 4];
        acc0a = __builtin_amdgcn_mfma_f32_16x16x32_bf16(a0, b00, acc0a, 0, 0, 0);
        acc1a = __builtin_amdgcn_mfma_f32_16x16x32_bf16(a0, b10, acc1a, 0, 0, 0);
        acc0b = __builtin_amdgcn_mfma_f32_16x16x32_bf16(a1, b01, acc0b, 0, 0, 0);
        acc1b = __builtin_amdgcn_mfma_f32_16x16x32_bf16(a1, b11, acc1b, 0, 0, 0);
    }
    f32x4 acc0 = acc0a + acc0b, acc1 = acc1a + acc1b;

    int rbase = mhalf * 16 + ((lane >> 4) << 2);
    int cix   = npair * 32 + (lane & 15);
    #pragma unroll
    for (int v = 0; v < 4; ++v) {                 // C/D map: col=lane&15, row=(lane>>4)*4+v
        gates[rbase + v][cix]      = acc0[v];
        gates[rbase + v][cix + 16] = acc1[v];
    }
    __syncthreads();

    // elementwise LSTM: thread -> hu = tid>>5, two local cols
    int hu  = tid >> 5;
    int hid = gg * 8 + hu;
    float bi  = b_ih[hid]        + b_hh[hid];
    float bf_ = b_ih[512 + hid]  + b_hh[512 + hid];
    float bgt = b_ih[1024 + hid] + b_hh[1024 + hid];
    float bo  = b_ih[1536 + hid] + b_hh[1536 + hid];
    #pragma unroll
    for (int u = 0; u < 2; ++u) {
        int bl = ((tid & 31) << 1) + u;
        int b  = bg * 64 + bl;
        int br = base_rows[b];
        bool fp = (br + stepi) >= LSEQ;
        float gi = gates[hu][bl]      + bi;
        float gf = gates[8 + hu][bl]  + bf_;
        float gc = gates[16 + hu][bl] + bgt;
        float go = gates[24 + hu][bl] + bo;
        float cold = c_st[(size_t)b * HIDD + hid];
        float c2 = sigm(gf) * cold + sigm(gi) * tanhf(gc);
        float h2 = sigm(go) * tanhf(c2);
        unsigned short hb;
        if (fp) {
            hb = xh_in[(size_t)b * KDIM + EMBD + hid];   // keep old h, keep c
        } else {
            hb = f2bf(h2);
            c_st[(size_t)b * HIDD + hid] = c2;
        }
        hstage[bl][hu] = hb;
    }
    __syncthreads();
    if (tid < 64) {
        int b = bg * 64 + tid;
        short8x hv = *((const short8x*)&hstage[tid][0]);
        *((short8x*)(xh_out + (size_t)b * KDIM + EMBD + gg * 8)) = hv;
    }
    // fused gather of next x: this WG handles batch element b = wg
    if (do_gather) {
        int b = wg;
        int br = base_rows[b];
        int row = br + stepi + 1; if (row > LSEQ - 1) row = LSEQ - 1;
        int tok = xs[(size_t)row * BATCH + b];
        float ev = embW[(size_t)tok * EMBD + tid] *
                   mask[((size_t)row * BATCH + b) * EMBD + tid];
        xh_out[(size_t)b * KDIM + tid] = f2bf(ev);
    }
}

// ---------------------------------------------------------------------------
// Boundary (after the 21st step of each outer iter): jump logits (41x512
// matvec) + base row, log-softmax, gumbel argmax, lp/base store, row update,
// then gather of next outer iter's first x. 4 WGs x 64 batch each.
// ---------------------------------------------------------------------------
__global__ __launch_bounds__(256) void boundary_kernel(
    unsigned short* xh,            // current buffer: h part read, x part written
    int* __restrict__ base_rows,
    const float* __restrict__ W_jump, const float* __restrict__ b_jump,
    const float* __restrict__ W_base, const float* __restrict__ b_base,
    const float* __restrict__ gumbel,
    float* __restrict__ lp_arr, float* __restrict__ base_arr,
    const int* __restrict__ xs, const float* __restrict__ embW,
    const float* __restrict__ mask,
    int n, int do_gather)
{
    __shared__ float zbuf[42][64];
    int bg = blockIdx.x, t = threadIdx.x;
    for (int idx = t; idx < 42 * 64; idx += 256) {
        int r = idx >> 6, bb = idx & 63;
        int b = bg * 64 + bb;
        const unsigned short* hp = xh + (size_t)b * KDIM + EMBD;
        const float* wr = (r < NJ) ? (W_jump + (size_t)r * HIDD) : W_base;
        float acc = 0.0f;
        for (int k = 0; k < HIDD; k += 8) {
            union { short8x v; unsigned short u[8]; } hv;
            hv.v = *(const short8x*)(hp + k);
            #pragma unroll
            for (int j = 0; j < 8; ++j) acc += wr[k + j] * bf2f(hv.u[j]);
        }
        acc += (r < NJ) ? b_jump[r] : b_base[0];
        zbuf[r][bb] = acc;
    }
    __syncthreads();
    if (t < 64) {
        int b = bg * 64 + t;
        const float* g = gumbel + ((size_t)n * BATCH + b) * NJ;
        float m = -1e30f, mg = -1e30f; int jm = 0;
        for (int r = 0; r < NJ; ++r) {
            float z = zbuf[r][t];
            if (z > m) m = z;
            float zg = z + g[r];
            if (zg > mg) { mg = zg; jm = r; }   // strict > = first-max tiebreak
        }
        float s = 0.0f;
        for (int r = 0; r < NJ; ++r) s += expf(zbuf[r][t] - m);
        float lse = m + logf(s);
        int br = base_rows[b];
        bool fp = (br + 20) >= LSEQ;
        lp_arr[n * BATCH + b]   = fp ? 0.0f : (zbuf[jm][t] - lse);
        base_arr[n * BATCH + b] = zbuf[41][t];
        int reff = br + 20; if (reff > LSEQ - 1) reff = LSEQ - 1;
        base_rows[b] = (jm == 0) ? LSEQ : (reff + jm);
    }
    __syncthreads();
    if (do_gather) {
        for (int bb = 0; bb < 64; ++bb) {
            int b = bg * 64 + bb;
            int br = base_rows[b];
            int row = (br > LSEQ - 1) ? (LSEQ - 1) : br;
            int tok = xs[(size_t)row * BATCH + b];
            float ev = embW[(size_t)tok * EMBD + t] *
                       mask[((size_t)row * BATCH + b) * EMBD + t];
            xh[(size_t)b * KDIM + t] = f2bf(ev);
        }
    }
}

// ---------------------------------------------------------------------------
// Final: y = log_softmax(h @ W_out.T + b_out); nll + reinforce + mse -> scalar
// ---------------------------------------------------------------------------
__global__ __launch_bounds__(256) void final_kernel(
    const unsigned short* __restrict__ xh,
    const float* __restrict__ W_out, const float* __restrict__ b_out,
    const int* __restrict__ tcls,
    const float* __restrict__ lp_arr, const float* __restrict__ base_arr,
    float* __restrict__ out)
{
    __shared__ float red[256];
    int b = threadIdx.x;
    const unsigned short* hp = xh + (size_t)b * KDIM + EMBD;
    float y[5];
    for (int c = 0; c < 5; ++c) {
        const float* wr = W_out + (size_t)c * HIDD;
        float acc = 0.0f;
        for (int k = 0; k < HIDD; k += 8) {
            union { short8x v; unsigned short u[8]; } hv;
            hv.v = *(const short8x*)(hp + k);
            #pragma unroll
            for (int j = 0; j < 8; ++j) acc += wr[k + j] * bf2f(hv.u[j]);
        }
        y[c] = acc + b_out[c];
    }
    float m = y[0]; int am = 0;
    for (int c = 1; c < 5; ++c) if (y[c] > m) { m = y[c]; am = c; }
    float s = 0.0f;
    for (int c = 0; c < 5; ++c) s += expf(y[c] - m);
    float lse = m + logf(s);
    int tb = tcls[b];
    float nll_p  = -(y[tb] - lse) * (1.0f / BATCH);
    float reward = (am == tb) ? 1.0f : -1.0f;
    float rp = 0.0f, mp = 0.0f;
    for (int nn = 0; nn < 5; ++nn) {
        float bs = base_arr[nn * BATCH + b];
        float lp = lp_arr[nn * BATCH + b];
        rp += -(reward - bs) * lp;
        float d = bs - reward;
        mp += d * d;
    }
    red[b] = nll_p + rp * (1.0f / (5.0f * BATCH)) + mp;
    __syncthreads();
    for (int off = 128; off > 0; off >>= 1) {
        if (b < off) red[b] += red[b + off];
        __syncthreads();
    }
    if (b == 0) out[0] = red[0];
}

// ---------------------------------------------------------------------------
extern "C" void kernel_launch(void* const* d_in, const int* in_sizes, int n_in,
                              void* d_out, int out_size, void* d_ws, size_t ws_size,
                              hipStream_t stream)
{
    (void)in_sizes; (void)n_in; (void)out_size; (void)ws_size;
    const int*   xs     = (const int*)d_in[0];
    // d_in[1] = lengths (unused by reference)
    const int*   tcls   = (const int*)d_in[2];
    const float* embW   = (const float*)d_in[3];
    const float* W_ih   = (const float*)d_in[4];
    const float* W_hh   = (const float*)d_in[5];
    const float* b_ih   = (const float*)d_in[6];
    const float* b_hh   = (const float*)d_in[7];
    const float* W_out  = (const float*)d_in[8];
    const float* b_out  = (const float*)d_in[9];
    const float* W_jump = (const float*)d_in[10];
    const float* b_jump = (const float*)d_in[11];
    const float* W_base = (const float*)d_in[12];
    const float* b_base = (const float*)d_in[13];
    const float* mask   = (const float*)d_in[14];
    const float* gumbel = (const float*)d_in[15];

    char* w = (char*)d_ws;
    unsigned short* pW  = (unsigned short*)(w);                 // 3,145,728 B
    unsigned short* xh  = (unsigned short*)(w + 3145728);       //   786,432 B (2 buffers)
    float* c_st         = (float*)(w + 3932160);                //   524,288 B
    int*   base_rows    = (int*)(w + 4456448);                  //     1,024 B
    float* lp_arr       = (float*)(w + 4457472);                //     5,120 B
    float* base_arr     = (float*)(w + 4462592);                //     5,120 B
    float* outp         = (float*)d_out;

    const size_t XH = (size_t)BATCH * KDIM;   // ushorts per xh buffer

    prologue_kernel<<<256, 256, 0, stream>>>(W_ih, W_hh, xs, embW, mask,
                                             pW, xh, c_st, base_rows);
    int p = 0;
    for (int s = 0; s < 105; ++s) {
        int i = s % 21;
        step_kernel<<<256, 256, 0, stream>>>(pW, xh + (size_t)p * XH, xh + (size_t)(p ^ 1) * XH,
                                             c_st, base_rows, b_ih, b_hh,
                                             xs, embW, mask, i, (i < 20) ? 1 : 0);
        p ^= 1;
        if (i == 20) {
            int n = s / 21;
            boundary_kernel<<<4, 256, 0, stream>>>(xh + (size_t)p * XH, base_rows,
                                                   W_jump, b_jump, W_base, b_base, gumbel,
                                                   lp_arr, base_arr, xs, embW, mask,
                                                   n, (n < 4) ? 1 : 0);
        }
    }
    final_kernel<<<1, 256, 0, stream>>>(xh + (size_t)p * XH, W_out, b_out, tcls,
                                        lp_arr, base_arr, outp);
}

// Round 2
// 1239.001 us; speedup vs baseline: 1.5112x; 1.5112x over previous
//
#include <hip/hip_runtime.h>

#define LSEQ 400
#define BATCH 256
#define EMBD 256
#define HIDD 512
#define KDIM 768   // EMB + HID
#define NJ 41      // K+1

typedef __attribute__((ext_vector_type(8))) short short8x;
typedef __attribute__((ext_vector_type(4))) float f32x4;

__device__ __forceinline__ float bf2f(unsigned short u) {
    union { unsigned int i; float f; } v; v.i = ((unsigned int)u) << 16; return v.f;
}
__device__ __forceinline__ unsigned short f2bf(float f) {
    union { float f; unsigned int i; } v; v.f = f;
    unsigned int x = v.i;
    return (unsigned short)((x + 0x7fffu + ((x >> 16) & 1u)) >> 16);
}
__device__ __forceinline__ float sigm(float x) { return 1.0f / (1.0f + __expf(-x)); }

// ---------------------------------------------------------------------------
// Prologue: pack W_ih|W_hh (f32) into bf16 MFMA-fragment order; init state.
// pW layout: [gg(64)][mt(2)][kt(24)][lane(64)] x short8, where the WG "gg"
// owns hidden units [gg*8, gg*8+8), local row r = mt*16 + (lane&15),
// gate = r>>3, hu = r&7, global row = gate*512 + gg*8 + hu,
// k = kt*32 + (lane>>4)*8 + j  (same bijection used on the B side).
// ---------------------------------------------------------------------------
__global__ __launch_bounds__(256) void prologue_kernel(
    const float* __restrict__ W_ih, const float* __restrict__ W_hh,
    const int* __restrict__ xs, const float* __restrict__ embW,
    const float* __restrict__ mask,
    unsigned short* __restrict__ pW, unsigned short* __restrict__ xh0,
    float* __restrict__ c_st, int* __restrict__ base_rows)
{
    int wg = blockIdx.x, t = threadIdx.x;
    int gg = wg >> 2, part = wg & 3;
    int lane = t & 63, sub = t >> 6;
    for (int q = 0; q < 3; ++q) {
        int f = sub * 3 + q;                 // 0..11
        int mt = f / 6, kt = part * 6 + (f % 6);
        int r = mt * 16 + (lane & 15);
        int gate = r >> 3, hu = r & 7;
        int grow = gate * 512 + gg * 8 + hu;
        int k0 = kt * 32 + ((lane >> 4) << 3);
        union { short8x v; unsigned short u[8]; } pk;
        #pragma unroll
        for (int j = 0; j < 8; ++j) {
            int k = k0 + j;
            float wv = (k < EMBD) ? W_ih[(size_t)grow * EMBD + k]
                                  : W_hh[(size_t)grow * HIDD + (k - EMBD)];
            pk.u[j] = f2bf(wv);
        }
        ((short8x*)pW)[((size_t)(gg * 2 + mt) * 24 + kt) * 64 + lane] = pk.v;
    }
    // per-batch state init (b = wg): x for step 0 (row 0), h=0, c=0, base=0
    int b = wg;
    int tok = xs[b];   // row 0
    float ev = embW[(size_t)tok * EMBD + t] * mask[(size_t)b * EMBD + t];
    xh0[(size_t)b * KDIM + t] = f2bf(ev);
    for (int e = t; e < HIDD; e += 256) {
        xh0[(size_t)b * KDIM + EMBD + e] = 0;
        c_st[(size_t)b * HIDD + e] = 0.0f;
    }
    if (t == 0) base_rows[b] = 0;
}

// ---------------------------------------------------------------------------
// One LSTM step. 256 WGs = 64 gate-groups (gg: 8 hidden units) x 4 batch
// groups (bg: 64 cols). Per WG: D(32x64) = Wslice(32x768) @ xh(768x64) via
// mfma_f32_16x16x32_bf16, LDS exchange, elementwise LSTM (freeze-aware),
// then fused gather of next step's x (one batch element per WG).
// ---------------------------------------------------------------------------
__global__ __launch_bounds__(256) void step_kernel(
    const unsigned short* __restrict__ pW,
    const unsigned short* __restrict__ xh_in,
    unsigned short* __restrict__ xh_out,
    float* __restrict__ c_st,
    const int* __restrict__ base_rows,
    const float* __restrict__ b_ih, const float* __restrict__ b_hh,
    const int* __restrict__ xs, const float* __restrict__ embW,
    const float* __restrict__ mask,
    int stepi, int do_gather)
{
    __shared__ float gates[32][65];
    __shared__ __align__(16) unsigned short hstage[64][8];

    int wg = blockIdx.x;
    int gg = wg >> 2, bg = wg & 3;
    int tid = threadIdx.x, lane = tid & 63, w = tid >> 6;
    int mhalf = w >> 1, npair = w & 1;

    const short8x* Ab = ((const short8x*)pW) + ((size_t)(gg * 2 + mhalf) * 24) * 64 + lane;
    int bcol0 = bg * 64 + npair * 32 + (lane & 15);
    int krow  = (lane >> 4) << 3;
    const short8x* B0 = (const short8x*)(xh_in + (size_t)bcol0 * KDIM + krow);
    const short8x* B1 = (const short8x*)(xh_in + (size_t)(bcol0 + 16) * KDIM + krow);

    f32x4 acc0a = {0,0,0,0}, acc0b = {0,0,0,0};
    f32x4 acc1a = {0,0,0,0}, acc1b = {0,0,0,0};
    #pragma unroll
    for (int kt = 0; kt < 24; kt += 2) {          // 2 chains to shorten dep latency
        short8x a0  = Ab[kt * 64];
        short8x a1  = Ab[(kt + 1) * 64];
        short8x b00 = B0[kt * 4];
        short8x b01 = B0[(kt + 1) * 4];
        short8x b10 = B1[kt * 4];
        short8x b11 = B1[(kt + 1) * 4];
        acc0a = __builtin_amdgcn_mfma_f32_16x16x32_bf16(a0, b00, acc0a, 0, 0, 0);
        acc1a = __builtin_amdgcn_mfma_f32_16x16x32_bf16(a0, b10, acc1a, 0, 0, 0);
        acc0b = __builtin_amdgcn_mfma_f32_16x16x32_bf16(a1, b01, acc0b, 0, 0, 0);
        acc1b = __builtin_amdgcn_mfma_f32_16x16x32_bf16(a1, b11, acc1b, 0, 0, 0);
    }
    f32x4 acc0 = acc0a + acc0b, acc1 = acc1a + acc1b;

    int rbase = mhalf * 16 + ((lane >> 4) << 2);
    int cix   = npair * 32 + (lane & 15);
    #pragma unroll
    for (int v = 0; v < 4; ++v) {                 // C/D map: col=lane&15, row=(lane>>4)*4+v
        gates[rbase + v][cix]      = acc0[v];
        gates[rbase + v][cix + 16] = acc1[v];
    }
    __syncthreads();

    // elementwise LSTM: thread -> hu = tid>>5, two local cols
    int hu  = tid >> 5;
    int hid = gg * 8 + hu;
    float bi  = b_ih[hid]        + b_hh[hid];
    float bf_ = b_ih[512 + hid]  + b_hh[512 + hid];
    float bgt = b_ih[1024 + hid] + b_hh[1024 + hid];
    float bo  = b_ih[1536 + hid] + b_hh[1536 + hid];
    #pragma unroll
    for (int u = 0; u < 2; ++u) {
        int bl = ((tid & 31) << 1) + u;
        int b  = bg * 64 + bl;
        int br = base_rows[b];
        bool fp = (br + stepi) >= LSEQ;
        float gi = gates[hu][bl]      + bi;
        float gf = gates[8 + hu][bl]  + bf_;
        float gc = gates[16 + hu][bl] + bgt;
        float go = gates[24 + hu][bl] + bo;
        float cold = c_st[(size_t)b * HIDD + hid];
        float c2 = sigm(gf) * cold + sigm(gi) * tanhf(gc);
        float h2 = sigm(go) * tanhf(c2);
        unsigned short hb;
        if (fp) {
            hb = xh_in[(size_t)b * KDIM + EMBD + hid];   // keep old h, keep c
        } else {
            hb = f2bf(h2);
            c_st[(size_t)b * HIDD + hid] = c2;
        }
        hstage[bl][hu] = hb;
    }
    __syncthreads();
    if (tid < 64) {
        int b = bg * 64 + tid;
        short8x hv = *((const short8x*)&hstage[tid][0]);
        *((short8x*)(xh_out + (size_t)b * KDIM + EMBD + gg * 8)) = hv;
    }
    // fused gather of next x: this WG handles batch element b = wg
    if (do_gather) {
        int b = wg;
        int br = base_rows[b];
        int row = br + stepi + 1; if (row > LSEQ - 1) row = LSEQ - 1;
        int tok = xs[(size_t)row * BATCH + b];
        float ev = embW[(size_t)tok * EMBD + tid] *
                   mask[((size_t)row * BATCH + b) * EMBD + tid];
        xh_out[(size_t)b * KDIM + tid] = f2bf(ev);
    }
}

// ---------------------------------------------------------------------------
// Boundary (after the 21st step of each outer iter). ONE WG PER BATCH ELEM
// (grid=256). Per WG: 42x512 matvec (4 waves x ~11 rows, float4 W loads,
// 64-lane shuffle reduce), softmax/gumbel-argmax by thread 0, row update,
// then coalesced 256-thread gather of next outer iter's first x.
// ---------------------------------------------------------------------------
__global__ __launch_bounds__(256) void boundary_kernel(
    unsigned short* xh,            // current buffer: h part read, x part written
    int* __restrict__ base_rows,
    const float* __restrict__ W_jump, const float* __restrict__ b_jump,
    const float* __restrict__ W_base, const float* __restrict__ b_base,
    const float* __restrict__ gumbel,
    float* __restrict__ lp_arr, float* __restrict__ base_arr,
    const int* __restrict__ xs, const float* __restrict__ embW,
    const float* __restrict__ mask,
    int n, int do_gather)
{
    __shared__ float zsh[42];
    __shared__ int rowsh;
    int b = blockIdx.x;
    int tid = threadIdx.x, lane = tid & 63, w = tid >> 6;

    // h in registers: lane holds k = lane*8 .. lane*8+7 (same for all 4 waves)
    const unsigned short* hp = xh + (size_t)b * KDIM + EMBD;
    union { short8x v; unsigned short u[8]; } hv;
    hv.v = *(const short8x*)(hp + lane * 8);
    float hf[8];
    #pragma unroll
    for (int j = 0; j < 8; ++j) hf[j] = bf2f(hv.u[j]);

    for (int r = w; r < 42; r += 4) {
        const float* wr = (r < NJ) ? (W_jump + (size_t)r * HIDD) : W_base;
        const float4* wp = (const float4*)(wr + lane * 8);
        float4 w0 = wp[0], w1 = wp[1];
        float acc = w0.x*hf[0] + w0.y*hf[1] + w0.z*hf[2] + w0.w*hf[3]
                  + w1.x*hf[4] + w1.y*hf[5] + w1.z*hf[6] + w1.w*hf[7];
        #pragma unroll
        for (int off = 32; off > 0; off >>= 1) acc += __shfl_down(acc, off, 64);
        if (lane == 0) zsh[r] = acc + ((r < NJ) ? b_jump[r] : b_base[0]);
    }
    __syncthreads();

    if (tid == 0) {
        const float* g = gumbel + ((size_t)n * BATCH + b) * NJ;
        float m = -1e30f, mg = -1e30f; int jm = 0;
        for (int r = 0; r < NJ; ++r) {
            float z = zsh[r];
            if (z > m) m = z;
            float zg = z + g[r];
            if (zg > mg) { mg = zg; jm = r; }   // strict > = first-max tiebreak
        }
        float s = 0.0f;
        for (int r = 0; r < NJ; ++r) s += expf(zsh[r] - m);
        float lse = m + logf(s);
        int br = base_rows[b];
        bool fp = (br + 20) >= LSEQ;
        lp_arr[n * BATCH + b]   = fp ? 0.0f : (zsh[jm] - lse);
        base_arr[n * BATCH + b] = zsh[41];
        int reff = br + 20; if (reff > LSEQ - 1) reff = LSEQ - 1;
        int nbr = (jm == 0) ? LSEQ : (reff + jm);
        base_rows[b] = nbr;
        rowsh = (nbr > LSEQ - 1) ? (LSEQ - 1) : nbr;
    }
    __syncthreads();

    if (do_gather) {
        int row = rowsh;
        int tok = xs[(size_t)row * BATCH + b];
        float ev = embW[(size_t)tok * EMBD + tid] *
                   mask[((size_t)row * BATCH + b) * EMBD + tid];
        xh[(size_t)b * KDIM + tid] = f2bf(ev);
    }
}

// ---------------------------------------------------------------------------
// Final: y = log_softmax(h @ W_out.T + b_out); nll + reinforce + mse -> scalar
// ---------------------------------------------------------------------------
__global__ __launch_bounds__(256) void final_kernel(
    const unsigned short* __restrict__ xh,
    const float* __restrict__ W_out, const float* __restrict__ b_out,
    const int* __restrict__ tcls,
    const float* __restrict__ lp_arr, const float* __restrict__ base_arr,
    float* __restrict__ out)
{
    __shared__ float red[256];
    int b = threadIdx.x;
    const unsigned short* hp = xh + (size_t)b * KDIM + EMBD;
    float y[5];
    for (int c = 0; c < 5; ++c) {
        const float* wr = W_out + (size_t)c * HIDD;
        float acc = 0.0f;
        for (int k = 0; k < HIDD; k += 8) {
            union { short8x v; unsigned short u[8]; } hv;
            hv.v = *(const short8x*)(hp + k);
            #pragma unroll
            for (int j = 0; j < 8; ++j) acc += wr[k + j] * bf2f(hv.u[j]);
        }
        y[c] = acc + b_out[c];
    }
    float m = y[0]; int am = 0;
    for (int c = 1; c < 5; ++c) if (y[c] > m) { m = y[c]; am = c; }
    float s = 0.0f;
    for (int c = 0; c < 5; ++c) s += expf(y[c] - m);
    float lse = m + logf(s);
    int tb = tcls[b];
    float nll_p  = -(y[tb] - lse) * (1.0f / BATCH);
    float reward = (am == tb) ? 1.0f : -1.0f;
    float rp = 0.0f, mp = 0.0f;
    for (int nn = 0; nn < 5; ++nn) {
        float bs = base_arr[nn * BATCH + b];
        float lp = lp_arr[nn * BATCH + b];
        rp += -(reward - bs) * lp;
        float d = bs - reward;
        mp += d * d;
    }
    red[b] = nll_p + rp * (1.0f / (5.0f * BATCH)) + mp;
    __syncthreads();
    for (int off = 128; off > 0; off >>= 1) {
        if (b < off) red[b] += red[b + off];
        __syncthreads();
    }
    if (b == 0) out[0] = red[0];
}

// ---------------------------------------------------------------------------
extern "C" void kernel_launch(void* const* d_in, const int* in_sizes, int n_in,
                              void* d_out, int out_size, void* d_ws, size_t ws_size,
                              hipStream_t stream)
{
    (void)in_sizes; (void)n_in; (void)out_size; (void)ws_size;
    const int*   xs     = (const int*)d_in[0];
    // d_in[1] = lengths (unused by reference)
    const int*   tcls   = (const int*)d_in[2];
    const float* embW   = (const float*)d_in[3];
    const float* W_ih   = (const float*)d_in[4];
    const float* W_hh   = (const float*)d_in[5];
    const float* b_ih   = (const float*)d_in[6];
    const float* b_hh   = (const float*)d_in[7];
    const float* W_out  = (const float*)d_in[8];
    const float* b_out  = (const float*)d_in[9];
    const float* W_jump = (const float*)d_in[10];
    const float* b_jump = (const float*)d_in[11];
    const float* W_base = (const float*)d_in[12];
    const float* b_base = (const float*)d_in[13];
    const float* mask   = (const float*)d_in[14];
    const float* gumbel = (const float*)d_in[15];

    char* w = (char*)d_ws;
    unsigned short* pW  = (unsigned short*)(w);                 // 3,145,728 B
    unsigned short* xh  = (unsigned short*)(w + 3145728);       //   786,432 B (2 buffers)
    float* c_st         = (float*)(w + 3932160);                //   524,288 B
    int*   base_rows    = (int*)(w + 4456448);                  //     1,024 B
    float* lp_arr       = (float*)(w + 4457472);                //     5,120 B
    float* base_arr     = (float*)(w + 4462592);                //     5,120 B
    float* outp         = (float*)d_out;

    const size_t XH = (size_t)BATCH * KDIM;   // ushorts per xh buffer

    prologue_kernel<<<256, 256, 0, stream>>>(W_ih, W_hh, xs, embW, mask,
                                             pW, xh, c_st, base_rows);
    int p = 0;
    for (int s = 0; s < 105; ++s) {
        int i = s % 21;
        step_kernel<<<256, 256, 0, stream>>>(pW, xh + (size_t)p * XH, xh + (size_t)(p ^ 1) * XH,
                                             c_st, base_rows, b_ih, b_hh,
                                             xs, embW, mask, i, (i < 20) ? 1 : 0);
        p ^= 1;
        if (i == 20) {
            int n = s / 21;
            boundary_kernel<<<256, 256, 0, stream>>>(xh + (size_t)p * XH, base_rows,
                                                     W_jump, b_jump, W_base, b_base, gumbel,
                                                     lp_arr, base_arr, xs, embW, mask,
                                                     n, (n < 4) ? 1 : 0);
        }
    }
    final_kernel<<<1, 256, 0, stream>>>(xh + (size_t)p * XH, W_out, b_out, tcls,
                                        lp_arr, base_arr, outp);
}